// Round 9
// baseline (565678.857 us; speedup 1.0000x reference)
//
#include <hip/hip_runtime.h>
#include <hip/hip_cooperative_groups.h>
#include <math.h>

namespace cg = cooperative_groups;

#define NA      1500
#define NEDGE   48000
#define NDIM    4500
#define NB      9
#define CLD     2560        /* unified chunk leading dim (cols) */
#define ZCHW    576
#define YLD     1152
#define CAPSM   640
#define CAP8    1152
#define SWEEPSB 8
#define NSWLOC  8
#define TSLOTS  196
#define SORTN   8192
#define COEFLD  864
#define NOUT    4494
#define PGRP    4
#define PI_D    3.14159265358979323846

// Chebyshev filter degrees per band
static const int H_DEG[NB] = {24, 48, 96, 160, 320, 320, 336, 336, 272};
#define DMAX0 320           /* max deg bands 0..4 */
#define DMAX1 336           /* max deg bands 5..8 */
__device__ __constant__ int d_DEG[NB] = {24, 48, 96, 160, 320, 320, 336, 336, 272};
__device__ __constant__ double d_MASS[10] = {1.008,4.003,6.941,9.012,10.811,12.011,14.007,15.999,18.998,20.18};
__device__ __constant__ double d_BLO[NB] = {31.04695, 9.84715, 6.37590, 5.08655, 4.39385, 3.86620, 3.34740, 2.87855, -1.0e9};
__device__ __constant__ double d_BHI[NB] = {1.0e9, 31.04695, 9.84715, 6.37590, 5.08655, 4.39385, 3.86620, 3.34740, 2.87855};

// ---------------- workspace layout (bytes) ----------------
// desc ints: [0..8]=NG, [16..25]=BOFF3 prefix, [48..56]=NBLK, [64+g*512+r]=atom lists
// (NOTE: indices >=64 are the atom lists — no scalar fields there! chunk fields live in O_COFF)
constexpr size_t O_WM   = 32768;
constexpr size_t O_MINV = O_WM + 12288;
constexpr size_t O_GER  = O_MINV + 12288;
constexpr size_t O_CH   = O_GER + 24576;
constexpr size_t O_COEF = O_CH + 256;                      // f64[9*864] zero-padded
constexpr size_t O_CMAP = O_COEF + (size_t)NB*COEFLD*8;    // int colband[2*CLD], colrow[2*CLD]
constexpr size_t O_COFF = O_CMAP + (size_t)4*CLD*4;        // int[16]: [g]=chunk-local col offset, [12+c]=nc
constexpr size_t O_DT   = O_COFF + 64;                     // f64[4500*9]
constexpr size_t O_PD   = O_DT + (size_t)NDIM*9*8;         // f64[9*1152*9]  X^T Dt
constexpr size_t O_EVA  = O_PD + (size_t)NB*1152*9*8;      // f64[8192]
constexpr size_t O_SID  = O_EVA + (size_t)SORTN*8;         // int[8192]
constexpr size_t O_HCOL = O_SID + (size_t)SORTN*4;         // int[1500*65]
constexpr size_t O_HV64 = O_HCOL + (size_t)NA*65*4;        // f64[1500*65*9]
constexpr size_t O_HV32 = O_HV64 + (size_t)NA*65*9*8;      // f32[1500*65*12]
constexpr size_t O_Y    = O_HV32 + (size_t)NA*65*12*4;     // f32[4500*2560]
constexpr size_t O_TA   = O_Y + (size_t)NDIM*CLD*4;        // f32[4500*2560]; aliases X1; later J
constexpr size_t O_TB   = O_TA + (size_t)NDIM*CLD*4;       // f32[4500*2560]; aliases X2; later RB
constexpr size_t O_S    = O_TB + (size_t)NDIM*CLD*4;       // f64[1152^2]; Z spans S..P
constexpr size_t O_P    = O_S + (size_t)CAP8*CAP8*8;
constexpr size_t O_G    = O_P + (size_t)CAP8*CAP8*8;
constexpr size_t GTOT   = (size_t)8*CAPSM*CAPSM + (size_t)CAP8*CAP8;
constexpr size_t WS_NEED = O_G + GTOT*8;                   // ~209.7 MB
constexpr size_t O_J    = O_TA;                            // alias (X1 dead)
constexpr size_t O_RB   = O_TB;                            // alias (X2 dead)

__host__ __device__ inline size_t goffd(int g){ return (g < 8) ? (size_t)g*CAPSM*CAPSM : (size_t)8*CAPSM*CAPSM; }
__host__ inline int capb(int g){ return (g < 8) ? CAPSM : CAP8; }

// ---------------- prep ----------------
__global__ void k_prep(const int* __restrict__ z, char* ws) {
  int* desc = (int*)ws;
  double* wm = (double*)(ws + O_WM);
  double* minv = (double*)(ws + O_MINV);
  __shared__ int zb[NA];
  __shared__ int cnt[NB];
  int tid = threadIdx.x;
  if (tid < NB) cnt[tid] = 0;
  __syncthreads();
  for (int a = tid; a < NA; a += blockDim.x) {
    int zz = z[a];
    int b = (zz >= 8) ? 8 : zz;
    zb[a] = b;
    atomicAdd(&cnt[b], 1);
    double m = d_MASS[zz];
    wm[a] = 1.0/sqrt(m);
    minv[a] = 1.0/m;
  }
  __syncthreads();
  if (tid == 0) {
    int off = 0;
    for (int g = 0; g < NB; ++g) {
      desc[16+g] = 3*off;
      int ng = 3*cnt[g];
      int cap = (g < 8) ? CAPSM : CAP8;
      ng = (ng > cap) ? cap : ng;
      desc[g] = ng;
      int nb = (ng + 15)/16;
      if (nb & 1) nb++;
      desc[48+g] = nb;
      off += cnt[g];
    }
    desc[16+NB] = 3*off;
  }
  __syncthreads();
  for (int a = tid; a < NA; a += blockDim.x) {
    int b = zb[a]; int r = 0;
    for (int x = 0; x < a; ++x) r += (zb[x] == b) ? 1 : 0;
    if (r < 512) desc[64 + b*512 + r] = a;
  }
}

// ---------------- column maps (chunk fields in O_COFF — NOT in desc!) ----------------
__global__ void k_cmap(char* ws) {
  int* desc = (int*)ws;
  int* coff = (int*)(ws + O_COFF);
  int* colband = (int*)(ws + O_CMAP);
  int* colrow = colband + 2*CLD;
  int tid = threadIdx.x;
  if (tid == 0) {
    int off0 = 0, off1 = 0;
    for (int g = 0; g < NB; ++g) {
      if (g < 5) { coff[g] = off0; off0 += desc[g]; }
      else       { coff[g] = off1; off1 += desc[g]; }
    }
    coff[12] = (off0 > CLD) ? CLD : off0;
    coff[13] = (off1 > CLD) ? CLD : off1;
  }
  __syncthreads();
  for (int g = 0; g < NB; ++g) {
    int c = (g < 5) ? 0 : 1;
    int lo = coff[g];
    int ng = desc[g];
    for (int l = tid; l < ng; l += blockDim.x) {
      int j = lo + l;
      if (j < CLD) {
        int atom = desc[64 + g*512 + l/3];
        colband[c*CLD + j] = g;
        colrow[c*CLD + j] = 3*atom + l%3;
      }
    }
  }
}

// ---------------- build sparse mass-weighted symmetrized H ----------------
__global__ void k_buildH(const int* __restrict__ ei, const float* __restrict__ Hi,
                         const float* __restrict__ Hij, char* ws) {
  int p = blockIdx.x, t = threadIdx.x;
  const double* wm = (const double*)(ws + O_WM);
  const double* minv = (const double*)(ws + O_MINV);
  int* hcol = (int*)(ws + O_HCOL);
  double* hv = (double*)(ws + O_HV64);
  float* hvf = (float*)(ws + O_HV32);
  __shared__ double rowabs[3][72];
  __shared__ double dcen[3];
  double v[9];
  int q = -1;
  if (t == 0) {
    q = p;
    double mi = minv[p];
    for (int a = 0; a < 3; ++a)
      for (int b = 0; b < 3; ++b)
        v[3*a+b] = 0.5*((double)Hi[9*p+3*a+b] + (double)Hi[9*p+3*b+a])*mi;
    for (int a = 0; a < 3; ++a) dcen[a] = v[3*a+a];
  } else if (t <= 32) {
    int off = t;
    int e = 32*p + off - 1;
    q = ei[e];
    double ww = 0.5*wm[p]*wm[q];
    for (int a = 0; a < 3; ++a)
      for (int b = 0; b < 3; ++b)
        v[3*a+b] = ww*(double)Hij[9*e+3*a+b];
  } else if (t <= 64) {
    int off = t - 32;
    int qr = (p + NA - off) % NA;
    int e = 32*qr + off - 1;
    q = ei[NEDGE + e];
    double ww = 0.5*wm[p]*wm[q];
    for (int a = 0; a < 3; ++a)
      for (int b = 0; b < 3; ++b)
        v[3*a+b] = ww*(double)Hij[9*e+3*b+a];
  }
  if (t < 65) {
    hcol[p*65+t] = q;
    for (int k = 0; k < 9; ++k) {
      hv[((size_t)p*65+t)*9+k] = v[k];
      hvf[((size_t)p*65+t)*12+k] = (float)v[k];
    }
    for (int k = 9; k < 12; ++k) hvf[((size_t)p*65+t)*12+k] = 0.0f;
    for (int a = 0; a < 3; ++a)
      rowabs[a][t] = fabs(v[3*a]) + fabs(v[3*a+1]) + fabs(v[3*a+2]);
  }
  __syncthreads();
  if (t == 0) {
    double hi = -1e300, lo = 1e300;
    for (int a = 0; a < 3; ++a) {
      double s = 0.0;
      for (int k = 0; k < 65; ++k) s += rowabs[a][k];
      double rad = s - fabs(dcen[a]);
      hi = fmax(hi, dcen[a] + rad);
      lo = fmin(lo, dcen[a] - rad);
    }
    double* ger = (double*)(ws + O_GER);
    ger[2*p] = hi; ger[2*p+1] = lo;
  }
}

// ---------------- spectrum bounds + Jackson-Chebyshev coefficients ----------------
__global__ void k_coeff(char* ws) {
  __shared__ double shi[256], slo[256];
  int tid = threadIdx.x;
  const double* ger = (const double*)(ws + O_GER);
  double hi = -1e300, lo = 1e300;
  for (int i = tid; i < NA; i += 256) { hi = fmax(hi, ger[2*i]); lo = fmin(lo, ger[2*i+1]); }
  shi[tid] = hi; slo[tid] = lo;
  __syncthreads();
  for (int s = 128; s > 0; s >>= 1) {
    if (tid < s) { shi[tid] = fmax(shi[tid], shi[tid+s]); slo[tid] = fmin(slo[tid], slo[tid+s]); }
    __syncthreads();
  }
  double* ch = (double*)(ws + O_CH);
  if (tid == 0) {
    double c = 0.5*(shi[0]+slo[0]);
    double h = 0.5*(shi[0]-slo[0])*1.002;
    ch[0] = c; ch[1] = h;
  }
  __syncthreads();
  double c = ch[0], h = ch[1];
  double* coef = (double*)(ws + O_COEF);
  for (int g = 0; g < NB; ++g) {
    int d = d_DEG[g];
    double xlo = fmin(1.0, fmax(-1.0, (d_BLO[g]-c)/h));
    double xhi = fmin(1.0, fmax(-1.0, (d_BHI[g]-c)/h));
    double f1 = acos(xlo), f2 = acos(xhi);
    double alp = PI_D/(double)(d+1);
    double ct = cos(alp)/sin(alp);
    for (int k = tid; k <= d; k += 256) {
      double ck = (k == 0) ? (f1-f2)/PI_D : 2.0*(sin(k*f1)-sin(k*f2))/(k*PI_D);
      double jk = ((double)(d+1-k)*cos(k*alp) + sin(k*alp)*ct)/(double)(d+1);
      coef[g*COEFLD+k] = ck*jk;
    }
  }
}

// ---------------- mass-weighted dipole/polar matrix Dt[4500][9] ----------------
__global__ void k_dt(const float* __restrict__ ded, const float* __restrict__ dep, char* ws) {
  int row = blockIdx.x*256 + threadIdx.x;
  if (row >= NDIM) return;
  int p = row/3, a = row%3;
  const double* wm = (const double*)(ws + O_WM);
  double w = wm[p];
  double* dt = (double*)(ws + O_DT) + (size_t)row*9;
  for (int cI = 0; cI < 3; ++cI) dt[cI] = w*(double)ded[9*p+3*a+cI];
  for (int cI = 0; cI < 6; ++cI) dt[3+cI] = w*(double)dep[18*p+6*a+cI];
}

// ---------------- scatter unit basis + gamma0 into Y (per chunk) ----------------
__global__ void k_x0u(char* ws, int c, float* __restrict__ Ta) {
  const int* coff = (const int*)(ws + O_COFF);
  int nc = coff[12+c];
  const int* colband = (const int*)(ws + O_CMAP) + c*CLD;
  const int* colrow = (const int*)(ws + O_CMAP) + 2*CLD + c*CLD;
  const double* coef = (const double*)(ws + O_COEF);
  float* Y = (float*)(ws + O_Y);
  for (int j = threadIdx.x; j < nc; j += blockDim.x) {
    int row = colrow[j];
    Ta[(size_t)row*CLD + j] = 1.0f;
    Y[(size_t)row*CLD + j] = (float)coef[colband[j]*COEFLD];
  }
}

// ---------------- unified Chebyshev tile ----------------
__device__ __forceinline__ void chebU_tile(char* ws, int c, int k, int first,
                                           const float* __restrict__ Tsrc,
                                           float* __restrict__ Tdst,
                                           float (* __restrict__ sval)[780],
                                           int ag, int half) {
  const int* coff = (const int*)(ws + O_COFF);
  int nc = coff[12+c];
  const double* ch = (const double*)(ws + O_CH);
  float ccf = (float)ch[0];
  float hinv = (float)(1.0/ch[1]);
  const double* coef = (const double*)(ws + O_COEF);
  const int* colband = (const int*)(ws + O_CMAP) + c*CLD;
  float* Y = (float*)(ws + O_Y);
  int tid = threadIdx.x;
  int p0 = ag*PGRP;
  int ncch = (nc + 511) >> 9;
  for (int cc = half; cc < ncch; cc += 2) {
    int c0 = cc << 9;
    int col0 = c0 + tid;
    int col1 = col0 + 256;
    bool v0 = (col0 < nc), v1 = (col1 < nc);
    int col1c = v1 ? col1 : col0;
    float gam0 = v0 ? (float)coef[colband[col0]*COEFLD + k] : 0.f;
    float gam1 = v1 ? (float)coef[colband[col1]*COEFLD + k] : 0.f;
    float acc0[PGRP][3] = {}, acc1[PGRP][3] = {};
    float xd0[PGRP][3], xd1[PGRP][3];
    for (int du = -32; du <= 32 + (PGRP-1); ++du) {
      int u = p0 + du;
      if (u < 0) u += NA;
      if (u >= NA) u -= NA;
      const float* xb = Tsrc + (size_t)(3*u)*CLD;
      float a0 = xb[col0], a1 = xb[CLD+col0], a2 = xb[2*CLD+col0];
      float b0 = xb[col1c], b1 = xb[CLD+col1c], b2 = xb[2*CLD+col1c];
      #pragma unroll
      for (int pp = 0; pp < PGRP; ++pp) {
        int off = du - pp;
        int t;
        if (off == 0) {
          t = 0;
          xd0[pp][0] = a0; xd0[pp][1] = a1; xd0[pp][2] = a2;
          xd1[pp][0] = b0; xd1[pp][1] = b1; xd1[pp][2] = b2;
        }
        else if (off >= 1 && off <= 32) t = off;
        else if (off >= -32 && off <= -1) t = 32 - off;
        else continue;
        const float* v = &sval[pp][t*12];
        float4 va = *(const float4*)v;
        float4 vb = *(const float4*)(v+4);
        float v8 = v[8];
        acc0[pp][0] += va.x*a0 + va.y*a1 + va.z*a2;
        acc0[pp][1] += va.w*a0 + vb.x*a1 + vb.y*a2;
        acc0[pp][2] += vb.z*a0 + vb.w*a1 + v8*a2;
        acc1[pp][0] += va.x*b0 + va.y*b1 + va.z*b2;
        acc1[pp][1] += va.w*b0 + vb.x*b1 + vb.y*b2;
        acc1[pp][2] += vb.z*b0 + vb.w*b1 + v8*b2;
      }
    }
    #pragma unroll
    for (int pp = 0; pp < PGRP; ++pp) {
      int p = p0 + pp;
      #pragma unroll
      for (int a = 0; a < 3; ++a) {
        size_t rbase = (size_t)(3*p+a)*CLD;
        if (v0) {
          float u = (acc0[pp][a] - ccf*xd0[pp][a])*hinv;
          float tp = Tdst[rbase + col0];
          float tn = first ? u : (2.0f*u - tp);
          Tdst[rbase + col0] = tn;
          Y[rbase + col0] += gam0*tn;
        }
        if (v1) {
          float u = (acc1[pp][a] - ccf*xd1[pp][a])*hinv;
          float tp = Tdst[rbase + col1];
          float tn = first ? u : (2.0f*u - tp);
          Tdst[rbase + col1] = tn;
          Y[rbase + col1] += gam1*tn;
        }
      }
    }
  }
}

__global__ __launch_bounds__(256) void k_chebUC(char* ws, int c, int dmax, float* Ta, float* Tb) {
  cg::grid_group grid = cg::this_grid();
  __shared__ __align__(16) float sval[PGRP][780];
  int bx = blockIdx.x;
  int ag = bx >> 1, half = bx & 1;
  {
    const float4* src4 = (const float4*)((const float*)(ws + O_HV32) + (size_t)(ag*PGRP)*780);
    float4* dst4 = (float4*)&sval[0][0];
    for (int l = threadIdx.x; l < PGRP*195; l += 256) dst4[l] = src4[l];
  }
  __syncthreads();
  for (int k = 1; k <= dmax; ++k) {
    const float* Tsrc = (k & 1) ? Ta : Tb;
    float* Tdst = (k & 1) ? Tb : Ta;
    chebU_tile(ws, c, k, (k == 1) ? 1 : 0, Tsrc, Tdst, sval, ag, half);
    grid.sync();
  }
}

__global__ __launch_bounds__(256) void k_chebUS(char* ws, int c, int k, float* Ta, float* Tb) {
  __shared__ __align__(16) float sval[PGRP][780];
  int ag = blockIdx.x, half = blockIdx.y;
  {
    const float4* src4 = (const float4*)((const float*)(ws + O_HV32) + (size_t)(ag*PGRP)*780);
    float4* dst4 = (float4*)&sval[0][0];
    for (int l = threadIdx.x; l < PGRP*195; l += 256) dst4[l] = src4[l];
  }
  __syncthreads();
  const float* Tsrc = (k & 1) ? Ta : Tb;
  float* Tdst = (k & 1) ? Tb : Ta;
  chebU_tile(ws, c, k, (k == 1) ? 1 : 0, Tsrc, Tdst, sval, ag, half);
}

// ---------------- Y chunk cols -> X2 f64 (band g) ----------------
__global__ void k_upcastB(char* ws, int g, double* __restrict__ X2) {
  const int* desc = (const int*)ws;
  const int* coff = (const int*)(ws + O_COFF);
  int ng = desc[g];
  int lo = coff[g];
  int cap = (g < 8) ? CAPSM : CAP8;
  const float* Y = (const float*)(ws + O_Y);
  size_t tot = (size_t)NDIM*cap;
  for (size_t i = (size_t)blockIdx.x*1024 + threadIdx.x; i < tot; i += (size_t)gridDim.x*1024) {
    int row = (int)(i / cap), l = (int)(i - (size_t)row*cap);
    X2[(size_t)row*YLD + l] = (l < ng) ? (double)Y[(size_t)row*CLD + lo + l] : 0.0;
  }
}

// ---------------- f64 SpMM ----------------
__global__ __launch_bounds__(256) void k_spmm64(char* ws, const double* __restrict__ X,
                                                double* __restrict__ Z, int cw) {
  __shared__ double sval[585];
  __shared__ int scol[65];
  int p = blockIdx.x;
  const double* hv = (const double*)(ws + O_HV64) + (size_t)p*585;
  const int* hcol = (const int*)(ws + O_HCOL) + p*65;
  for (int l = threadIdx.x; l < 585; l += 256) sval[l] = hv[l];
  if (threadIdx.x < 65) scol[threadIdx.x] = hcol[threadIdx.x];
  __syncthreads();
  int col = blockIdx.y*256 + threadIdx.x;
  if (col >= cw) return;
  double a0 = 0.0, a1 = 0.0, a2 = 0.0;
  for (int t = 0; t < 65; ++t) {
    int q = scol[t];
    const double* xb = X + (size_t)(3*q)*YLD + col;
    double x0 = xb[0], x1 = xb[YLD], x2 = xb[2*YLD];
    const double* v = sval + t*9;
    a0 += v[0]*x0 + v[1]*x1 + v[2]*x2;
    a1 += v[3]*x0 + v[4]*x1 + v[5]*x2;
    a2 += v[6]*x0 + v[7]*x1 + v[8]*x2;
  }
  Z[(size_t)(3*p+0)*ZCHW + col] = a0;
  Z[(size_t)(3*p+1)*ZCHW + col] = a1;
  Z[(size_t)(3*p+2)*ZCHW + col] = a2;
}

// ---------------- f64 GEMMs ----------------
__global__ __launch_bounds__(256) void gemm_tn(const double* __restrict__ A, const double* __restrict__ B,
                                               double* __restrict__ C,
                                               int M, int N, int K, int lda, int ldb, int ldc) {
  __shared__ double As[16][66];
  __shared__ double Bs[16][66];
  int tid = threadIdx.x;
  int tx = tid & 15, ty = tid >> 4;
  int i0 = blockIdx.x*64, j0 = blockIdx.y*64;
  double acc[4][4] = {};
  for (int k0 = 0; k0 < K; k0 += 16) {
    for (int l = tid; l < 1024; l += 256) {
      int r = l >> 6, c = l & 63;
      int kk = k0 + r;
      As[r][c] = (kk < K && i0+c < M) ? A[(size_t)kk*lda + i0+c] : 0.0;
    }
    for (int l = tid; l < 1024; l += 256) {
      int r = l >> 6, c = l & 63;
      int kk = k0 + r;
      Bs[r][c] = (kk < K && j0+c < N) ? B[(size_t)kk*ldb + j0+c] : 0.0;
    }
    __syncthreads();
    for (int kk = 0; kk < 16; ++kk) {
      double a[4], b[4];
      #pragma unroll
      for (int i = 0; i < 4; ++i) { a[i] = As[kk][4*ty+i]; b[i] = Bs[kk][4*tx+i]; }
      #pragma unroll
      for (int i = 0; i < 4; ++i)
        #pragma unroll
        for (int j = 0; j < 4; ++j) acc[i][j] += a[i]*b[j];
    }
    __syncthreads();
  }
  for (int i = 0; i < 4; ++i) {
    int ii = i0 + 4*ty + i;
    if (ii >= M) continue;
    for (int j = 0; j < 4; ++j) {
      int jj = j0 + 4*tx + j;
      if (jj < N) C[(size_t)ii*ldc + jj] = acc[i][j];
    }
  }
}

__global__ __launch_bounds__(256) void gemm_nn(const double* __restrict__ A, const double* __restrict__ B,
                                               double* __restrict__ C,
                                               int M, int N, int K, int lda, int ldb, int ldc) {
  __shared__ double As[16][66];
  __shared__ double Bs[16][66];
  int tid = threadIdx.x;
  int tx = tid & 15, ty = tid >> 4;
  int i0 = blockIdx.x*64, j0 = blockIdx.y*64;
  double acc[4][4] = {};
  for (int k0 = 0; k0 < K; k0 += 16) {
    for (int l = tid; l < 1024; l += 256) {
      int r = l & 15, c = l >> 4;
      As[r][c] = ((i0+c) < M && (k0+r) < K) ? A[(size_t)(i0+c)*lda + k0+r] : 0.0;
    }
    for (int l = tid; l < 1024; l += 256) {
      int r = l >> 6, c = l & 63;
      Bs[r][c] = ((k0+r) < K && (j0+c) < N) ? B[(size_t)(k0+r)*ldb + j0+c] : 0.0;
    }
    __syncthreads();
    for (int kk = 0; kk < 16; ++kk) {
      double a[4], b[4];
      #pragma unroll
      for (int i = 0; i < 4; ++i) { a[i] = As[kk][4*ty+i]; b[i] = Bs[kk][4*tx+i]; }
      #pragma unroll
      for (int i = 0; i < 4; ++i)
        #pragma unroll
        for (int j = 0; j < 4; ++j) acc[i][j] += a[i]*b[j];
    }
    __syncthreads();
  }
  for (int i = 0; i < 4; ++i) {
    int ii = i0 + 4*ty + i;
    if (ii >= M) continue;
    for (int j = 0; j < 4; ++j) {
      int jj = j0 + 4*tx + j;
      if (jj < N) C[(size_t)ii*ldc + jj] = acc[i][j];
    }
  }
}

__global__ void k_pbuild(double* P, const double* S, int cap) {
  size_t idx = (size_t)blockIdx.x*256 + threadIdx.x;
  if (idx >= (size_t)cap*cap) return;
  int r = (int)(idx / cap), cI = (int)(idx % cap);
  P[idx] = (15.0*(r==cI ? 1.0 : 0.0) - 10.0*S[idx] + 3.0*P[idx])*0.125;
}

__global__ void k_jinit(double* J, int cap) {
  size_t idx = (size_t)blockIdx.x*256 + threadIdx.x;
  if (idx >= (size_t)cap*cap) return;
  int r = (int)(idx / cap), cI = (int)(idx % cap);
  J[idx] = (r==cI) ? 1.0 : 0.0;
}

// ---------------- block one-sided Jacobi (rotates G and J) ----------------
__global__ __launch_bounds__(256) void k_bjac(char* ws) {
  cg::grid_group grid = cg::this_grid();
  const int* desc = (const int*)ws;
  double* Gb = (double*)(ws + O_G);
  double* Jb = (double*)(ws + O_J);
  __shared__ double Wm[32][33];
  __shared__ double Vm[32][33];
  __shared__ double Cs[64][33];
  int tid = threadIdx.x;
  int tx = tid & 15, ty = tid >> 4;
  int mmax = 1;
  for (int g = 0; g < NB; ++g) {
    int nb = desc[48+g];
    if (nb >= 2 && nb-1 > mmax) mmax = nb-1;
  }
  int RT = SWEEPSB*mmax;
  for (int r = 0; r < RT; ++r) {
    int t = blockIdx.x;
    int g, k;
    if (t < 160) { g = t/20; k = t%20; } else { g = 8; k = t-160; }
    int nb = desc[48+g];
    int ng = desc[g];
    bool active = (nb >= 2);
    int m = active ? nb-1 : 1;
    if (!active || r >= SWEEPSB*m || k >= nb/2) active = false;
    if (active) {
      int rr = r % m;
      int I, J;
      if (k == 0) { I = m; J = rr; }
      else { I = (rr + k) % m; J = (rr + m - k) % m; }
      int cI = I*16, cJ = J*16;
      if (cI >= ng && cJ >= ng) active = false;
      if (active) {
        int cap = (g < 8) ? CAPSM : CAP8;
        size_t base = goffd(g);
        double* G = Gb + base;
        double* Jm2 = Jb + base;
        double w00=0.0, w01=0.0, w10=0.0, w11=0.0;
        for (int i0 = 0; i0 < ng; i0 += 64) {
          for (int l = tid; l < 2048; l += 256) {
            int rw = l & 63, j = l >> 6;
            int cidx = (j < 16) ? cI + j : cJ + (j-16);
            int i = i0 + rw;
            Cs[rw][j] = (i < ng) ? G[(size_t)cidx*cap + i] : 0.0;
          }
          __syncthreads();
          #pragma unroll 8
          for (int rw = 0; rw < 64; ++rw) {
            double a0 = Cs[rw][ty], a1 = Cs[rw][ty+16];
            double b0 = Cs[rw][tx], b1 = Cs[rw][tx+16];
            w00 += a0*b0; w01 += a0*b1; w10 += a1*b0; w11 += a1*b1;
          }
          __syncthreads();
        }
        Wm[ty][tx] = w00;      Wm[ty][tx+16] = w01;
        Wm[ty+16][tx] = w10;   Wm[ty+16][tx+16] = w11;
        Vm[ty][tx] = (ty==tx) ? 1.0 : 0.0;
        Vm[ty][tx+16] = 0.0;
        Vm[ty+16][tx] = 0.0;
        Vm[ty+16][tx+16] = (ty==tx) ? 1.0 : 0.0;
        __syncthreads();
        int pid = ty, sub = tx;
        for (int sw = 0; sw < NSWLOC; ++sw) {
          for (int rr2 = 0; rr2 < 31; ++rr2) {
            int p2, q2;
            if (pid == 0) { p2 = 31; q2 = rr2; }
            else { p2 = (rr2 + pid) % 31; q2 = (rr2 + 31 - pid) % 31; }
            double wpp = Wm[p2][p2], wqq = Wm[q2][q2], wpq = Wm[p2][q2];
            double cr = 1.0, sr = 0.0;
            bool rot = (wpq*wpq > 1e-28*fabs(wpp*wqq) + 1e-280);
            if (rot) {
              double tau = (wqq - wpp)/(2.0*wpq);
              double tt = (tau >= 0.0 ? 1.0 : -1.0)/(fabs(tau) + sqrt(1.0 + tau*tau));
              cr = 1.0/sqrt(1.0 + tt*tt);
              sr = tt*cr;
            }
            __syncthreads();
            if (rot) {
              #pragma unroll
              for (int cc2 = 0; cc2 < 2; ++cc2) {
                int c2 = sub + 16*cc2;
                double u = Wm[p2][c2], v = Wm[q2][c2];
                Wm[p2][c2] = cr*u - sr*v;
                Wm[q2][c2] = sr*u + cr*v;
              }
            }
            __syncthreads();
            if (rot) {
              #pragma unroll
              for (int cc2 = 0; cc2 < 2; ++cc2) {
                int rw = sub + 16*cc2;
                double u = Wm[rw][p2], v = Wm[rw][q2];
                Wm[rw][p2] = cr*u - sr*v;
                Wm[rw][q2] = sr*u + cr*v;
                u = Vm[rw][p2]; v = Vm[rw][q2];
                Vm[rw][p2] = cr*u - sr*v;
                Vm[rw][q2] = sr*u + cr*v;
              }
            }
            __syncthreads();
          }
        }
        for (int i = tid; i < ng; i += 256) {
          double bg[32];
          #pragma unroll 8
          for (int rw = 0; rw < 32; ++rw) {
            int cidx = (rw < 16) ? cI + rw : cJ + (rw-16);
            bg[rw] = G[(size_t)cidx*cap + i];
          }
          for (int p = 0; p < 32; ++p) {
            double s = 0.0;
            #pragma unroll 8
            for (int rw = 0; rw < 32; ++rw) s += bg[rw]*Vm[rw][p];
            int cidx = (p < 16) ? cI + p : cJ + (p-16);
            G[(size_t)cidx*cap + i] = s;
          }
          #pragma unroll 8
          for (int rw = 0; rw < 32; ++rw) {
            int cidx = (rw < 16) ? cI + rw : cJ + (rw-16);
            bg[rw] = Jm2[(size_t)cidx*cap + i];
          }
          for (int p = 0; p < 32; ++p) {
            double s = 0.0;
            #pragma unroll 8
            for (int rw = 0; rw < 32; ++rw) s += bg[rw]*Vm[rw][p];
            int cidx = (p < 16) ? cI + p : cJ + (p-16);
            Jm2[(size_t)cidx*cap + i] = s;
          }
        }
      }
    }
    grid.sync();
  }
}

// ---------------- eigenvalues: lambda_k = J_k . G_k ----------------
__global__ void k_eig(char* ws) {
  const int* desc = (const int*)ws;
  double* eva = (double*)(ws + O_EVA);
  int* sid = (int*)(ws + O_SID);
  int wv = (blockIdx.x*blockDim.x + threadIdx.x) >> 6;
  int lane = threadIdx.x & 63;
  if (wv >= SORTN) return;
  if (wv >= NDIM) {
    if (lane == 0) { eva[wv] = 1e300; sid[wv] = wv; }
    return;
  }
  int g = 0;
  while (g < 8 && wv >= desc[16+g+1]) ++g;
  int k = wv - desc[16+g];
  int cap = (g < 8) ? CAPSM : CAP8;
  int ng = desc[g];
  size_t base = goffd(g) + (size_t)k*cap;
  const double* G = (const double*)(ws + O_G) + base;
  const double* J = (const double*)(ws + O_J) + base;
  double acc = 0.0;
  for (int i = lane; i < ng; i += 64) acc += J[i]*G[i];
  for (int s = 32; s > 0; s >>= 1) acc += __shfl_xor(acc, s, 64);
  if (lane == 0) { eva[wv] = acc; sid[wv] = wv; }
}

// ---------------- single-block bitonic sort ----------------
__global__ void k_sort(char* ws) {
  double* key = (double*)(ws + O_EVA);
  int* val = (int*)(ws + O_SID);
  int tid = threadIdx.x;
  for (int size = 2; size <= SORTN; size <<= 1) {
    for (int stride = size >> 1; stride > 0; stride >>= 1) {
      __syncthreads();
      for (int t = tid; t < SORTN/2; t += 1024) {
        int i = 2*t - (t & (stride-1));
        int j = i + stride;
        bool up = ((i & size) == 0);
        double ki = key[i], kj = key[j];
        if ((ki > kj) == up) {
          key[i] = kj; key[j] = ki;
          int v = val[i]; val[i] = val[j]; val[j] = v;
        }
      }
    }
  }
}

// ---------------- final: freq, ir, raman ----------------
__global__ void k_final(char* ws, float* __restrict__ out) {
  int m = blockIdx.x*256 + threadIdx.x;
  if (m >= NOUT) return;
  const int* desc = (const int*)ws;
  const double* eva = (const double*)(ws + O_EVA);
  const int* sid = (const int*)(ws + O_SID);
  int s = m + 6;
  double lam = eva[s];
  int gid = sid[s];
  int g = 0;
  while (g < 8 && gid >= desc[16+g+1]) ++g;
  int k = gid - desc[16+g];
  const double* R = (const double*)(ws + O_RB) + ((size_t)g*1152 + k)*9;
  double q0 = R[0], q1 = R[1], q2 = R[2];
  double ir = 42.2561*(q0*q0 + q1*q1 + q2*q2);
  double xx = R[3], xy = R[4], yy = R[5], xz = R[6], zy = R[7], zz = R[8];
  double alpha = (xx + yy + zz)/3.0;
  double gsq = 0.5*((xx-yy)*(xx-yy) + (yy-zz)*(yy-zz) + (zz-xx)*(zz-xx))
             + 3.0*(xy*xy + xz*xz + zy*zy);
  double raman = (45.0*alpha*alpha + 7.0*gsq)*0.078424;
  double freq = sqrt(fmax(lam, 0.0)*9.375829e28)/(2.0*PI_D)/2.9979245800e10*0.965;
  out[m] = (float)freq;
  out[NOUT + m] = (float)ir;
  out[2*NOUT + m] = (float)raman;
}

__global__ void k_fail(float* out) {
  int i = blockIdx.x*256 + threadIdx.x;
  if (i < 3*NOUT) out[i] = -7777.0f;
}

// ---------------- host ----------------
extern "C" void kernel_launch(void* const* d_in, const int* in_sizes, int n_in,
                              void* d_out, int out_size, void* d_ws, size_t ws_size,
                              hipStream_t stream) {
  const int* z = (const int*)d_in[1];
  const int* ei = (const int*)d_in[2];
  const float* Hi = (const float*)d_in[3];
  const float* Hij = (const float*)d_in[4];
  const float* ded = (const float*)d_in[5];
  const float* dep = (const float*)d_in[6];
  float* out = (float*)d_out;
  char* ws = (char*)d_ws;

  if (ws_size < WS_NEED) {
    k_fail<<<(3*NOUT+255)/256, 256, 0, stream>>>(out);
    return;
  }

  hipMemsetAsync(ws, 0, O_HCOL, stream);
  k_prep<<<1, 256, 0, stream>>>(z, ws);
  k_cmap<<<1, 256, 0, stream>>>(ws);
  k_buildH<<<NA, 128, 0, stream>>>(ei, Hi, Hij, ws);
  k_coeff<<<1, 256, 0, stream>>>(ws);
  k_dt<<<(NDIM+255)/256, 256, 0, stream>>>(ded, dep, ws);

  float* TA = (float*)(ws + O_TA);
  float* TB = (float*)(ws + O_TB);
  double* X1 = (double*)(ws + O_TA);
  double* X2 = (double*)(ws + O_TB);
  double* Sb = (double*)(ws + O_S);
  double* Pb = (double*)(ws + O_P);
  double* Zb = (double*)(ws + O_S);
  double* Dt = (double*)(ws + O_DT);

  const int dmaxc[2] = {DMAX0, DMAX1};
  for (int c = 0; c < 2; ++c) {
    hipMemsetAsync((void*)(ws + O_Y), 0, (size_t)NDIM*CLD*4, stream);
    hipMemsetAsync((void*)TA, 0, (size_t)NDIM*CLD*4, stream);
    hipMemsetAsync((void*)TB, 0, (size_t)NDIM*CLD*4, stream);
    k_x0u<<<1, 1024, 0, stream>>>(ws, c, TA);
    {
      int dm = dmaxc[c];
      void* args[] = { (void*)&ws, (void*)&c, (void*)&dm, (void*)&TA, (void*)&TB };
      hipError_t ce = hipLaunchCooperativeKernel((void*)k_chebUC, dim3(2*(NA/PGRP)), dim3(256), args, 0, stream);
      if (ce != hipSuccess) {
        (void)hipGetLastError();
        for (int k = 1; k <= dm; ++k)
          k_chebUS<<<dim3(NA/PGRP, 2), 256, 0, stream>>>(ws, c, k, TA, TB);
      }
    }
    int g0 = (c == 0) ? 0 : 5, g1 = (c == 0) ? 5 : 9;
    for (int g = g0; g < g1; ++g) {
      int cap = capb(g);
      k_upcastB<<<512, 1024, 0, stream>>>(ws, g, X2);
      double* Xa = X2; double* Xb = X1;
      dim3 gsq((cap+63)/64, (cap+63)/64);
      for (int it = 0; it < 5; ++it) {
        gemm_tn<<<gsq, 256, 0, stream>>>(Xa, Xa, Sb, cap, cap, NDIM, YLD, YLD, cap);
        gemm_nn<<<gsq, 256, 0, stream>>>(Sb, Sb, Pb, cap, cap, cap, cap, cap, cap);
        k_pbuild<<<((size_t)cap*cap + 255)/256, 256, 0, stream>>>(Pb, Sb, cap);
        gemm_nn<<<dim3((NDIM+63)/64, (cap+63)/64), 256, 0, stream>>>(Xa, Pb, Xb, NDIM, cap, cap, YLD, cap, YLD);
        double* tmp = Xa; Xa = Xb; Xb = tmp;
      }
      // PD_g = X^T Dt
      gemm_tn<<<dim3((cap+63)/64, 1), 256, 0, stream>>>(Xa, Dt,
          (double*)(ws + O_PD) + (size_t)g*1152*9, cap, 9, NDIM, YLD, 9, 9);
      // Heff_g = X^T (H X) chunked
      double* Gg = (double*)(ws + O_G) + goffd(g);
      for (int zc = 0; zc < 2; ++zc) {
        int c0 = zc*ZCHW;
        int cwz = cap - c0; if (cwz > ZCHW) cwz = ZCHW;
        if (cwz <= 0) break;
        dim3 gz(NA, (cwz + 255)/256);
        k_spmm64<<<gz, 256, 0, stream>>>(ws, Xa + c0, Zb, cwz);
        gemm_tn<<<dim3((cap+63)/64, (cwz+63)/64), 256, 0, stream>>>(Xa, Zb, Gg + c0,
            cap, cwz, NDIM, YLD, ZCHW, cap);
      }
    }
  }

  // init J = I per band (J aliases TA region; X1 dead now)
  for (int g = 0; g < NB; ++g) {
    int cap = capb(g);
    k_jinit<<<((size_t)cap*cap + 255)/256, 256, 0, stream>>>((double*)(ws + O_J) + goffd(g), cap);
  }

  // joint block one-sided Jacobi (G and J)
  {
    void* args[] = { (void*)&ws };
    hipLaunchCooperativeKernel((void*)k_bjac, dim3(TSLOTS), dim3(256), args, 0, stream);
  }

  k_eig<<<(SORTN*64)/256, 256, 0, stream>>>(ws);
  k_sort<<<1, 1024, 0, stream>>>(ws);

  // R_g = J^T-composed modes dotted with PD (RB aliases TB; X2 dead)
  for (int g = 0; g < NB; ++g) {
    int cap = capb(g);
    gemm_nn<<<dim3((cap+63)/64, 1), 256, 0, stream>>>(
        (double*)(ws + O_J) + goffd(g),
        (double*)(ws + O_PD) + (size_t)g*1152*9,
        (double*)(ws + O_RB) + (size_t)g*1152*9,
        cap, 9, cap, cap, 9, 9);
  }
  k_final<<<(NOUT+255)/256, 256, 0, stream>>>(ws, out);
}